// Round 8
// baseline (98.556 us; speedup 1.0000x reference)
//
#include <hip/hip_runtime.h>
#include <math.h>

#define NW 14
#define NSTATE 16384
#define HALF 8192
#define NL 4
#define BATCH 128
#define TPB 1024
// psi 64 KB + spare 32 KB + spare2 32 KB dynamic LDS -> 128 KB, 1 blk/CU.
#define SHB ((2 * HALF) * (int)sizeof(float2))

// ---------------------------------------------------------------------------
// Wire w <-> index bit (13-w). Ring composite R (verified r1):
//   y_p = x_p^x_{p+1} (p<=11), y12 = x12^x13^x0, y13 = x13^x0.
//
// r20 = r19 (98.1us total; writer-parity split, kernel <45.4us) + SPARE2
// stash closing the last redundant exchange leg. Audit: at boundary 2 each
// block writes its partner-half items (rd, ODD local addresses: writer =
// bit0^bit13, so partner-half odd == self-written) to global, then phase 3
// RE-READS those same items from global as the odd part of its partner-half
// reads. Fix: also stash rd in spare2 (32KB LDS); phase-3 partner-half read
// = 4 global (even locals, partner-written) + 4 LDS (odd locals, ours).
// Boundary-2 global reads 24->16MB; phase-3 entry 12->8 global loads/thread.
// Writes stay 16MB (partner genuinely needs both ld and rd: ld = its
// partner-half evens, rd = its own-half odds).
// Exchange totals: B1 8W+8R, B2 16W+16R = 48MB unique (was 56 in r19,
// 80 in r16). Gate math r16 verbatim; sync r16 verbatim (r17/r18 proved
// boundary mechanics ~free).
// Timing model: dur = ~45.6us poison fill (fixed) + kernel + ~10us gaps.
// ---------------------------------------------------------------------------

#define MAGIC64 0x9E3779B97F4A7C15ull

typedef float v2f __attribute__((ext_vector_type(2)));

// Compile-time scheduling fence only (no runtime cost).
#define WAVE_FENCE() __builtin_amdgcn_wave_barrier()

__device__ __forceinline__ unsigned sxmap(unsigned v) {   // v: bits 0..11
    unsigned t = v;
    t ^= t >> 1; t ^= t >> 2; t ^= t >> 4; t ^= t >> 8;
    return (t & 0x0FFFu) | ((t & 1u) << 13);              // = Rinv(v)
}

__device__ __forceinline__ float2 cmul(float2 u, float2 v) {
    return make_float2(u.x * v.x - u.y * v.y, u.x * v.y + u.y * v.x);
}

// Agent-coherent (L2-bypassing, sc1) 8-byte store/load for cross-XCD data.
__device__ __forceinline__ void st_agent(float2* p, float2 v) {
    __hip_atomic_store(reinterpret_cast<unsigned long long*>(p),
                       __builtin_bit_cast(unsigned long long, v),
                       __ATOMIC_RELAXED, __HIP_MEMORY_SCOPE_AGENT);
}
__device__ __forceinline__ float2 ld_agent(const float2* p) {
    unsigned long long u = __hip_atomic_load(
        reinterpret_cast<const unsigned long long*>(p),
        __ATOMIC_RELAXED, __HIP_MEMORY_SCOPE_AGENT);
    return __builtin_bit_cast(float2, u);
}

// Fused 1q gate G = RZ(t2)*RX(t1) (layer 0 folds data RX; verified r1-r11).
__device__ __forceinline__ float4 fused_coef(const float* weights,
                                             const float* states,
                                             int b, int l, int w) {
    float t1 = weights[(l * NW + w) * 2 + 0];
    float t2 = weights[(l * NW + w) * 2 + 1];
    if (l == 0) t1 += fabsf(states[(size_t)b * NSTATE + w]);
    float s, c, sz, cz;
    sincosf(0.5f * t1, &s, &c);
    sincosf(0.5f * t2, &sz, &cz);
    return make_float4(c * cz, -c * sz, -s * sz, -s * cz);
}

// SU(2) gate on register pairs (k,k|M); s3&M -> X-conjugated (verified r3+).
// r16 form: v2f ext-vector arithmetic, compiler-scheduled (fastest measured).
template<int N, int M>
__device__ __forceinline__ void gateN(float2* rr, float4 g, unsigned s3) {
    const float f = (s3 & (unsigned)M) ? -1.0f : 1.0f;
    const v2f gx = {g.x, g.x};
    const v2f gy = {f * g.y, f * g.y};
    const v2f gz = {f * g.z, f * g.z};
    const v2f gw = {g.w, g.w};
    v2f* r = (v2f*)rr;
#pragma unroll
    for (int k = 0; k < N; ++k) {
        if ((k & M) == 0) {
            const v2f z0 = r[k], z1 = r[k|M];
            const v2f z0s = {-z0.y, z0.x};
            const v2f z1s = {-z1.y, z1.x};
            r[k]   = gx*z0 + gy*z0s + gz*z1 + gw*z1s;
            r[k|M] = gx*z1 - gy*z1s - gz*z0 + gw*z0s;
        }
    }
}

// 3-bit pass over the 13-bit HALF-state (r9 verbatim).
template<int J0, int S3SH, int S3MSK>
__device__ __forceinline__ void pass3h(float2* psi, const float4* gc,
                                       unsigned t) {
    const float4 gA = gc[13 - (J0 + 0)];
    const float4 gB = gc[13 - (J0 + 1)];
    const float4 gC = gc[13 - (J0 + 2)];
    const unsigned s3   = (t >> S3SH) & (unsigned)S3MSK;
    const unsigned low  = t & ((1u << J0) - 1u);
    const unsigned high = (t >> J0) << (J0 + 3);
    float2 r[8];
#pragma unroll
    for (int k = 0; k < 8; ++k)
        r[k] = psi[low | (((unsigned)k ^ s3) << J0) | high];
    gateN<8,1>(r, gA, s3);
    gateN<8,2>(r, gB, s3);
    gateN<8,4>(r, gC, s3);
#pragma unroll
    for (int k = 0; k < 8; ++k)
        psi[low | (((unsigned)k ^ s3) << J0) | high] = r[k];
}

// Wire-1 gate + Rinv-relabel scatter with writer-parity split.
// DUAL=false (boundary 1): self-destined -> spare; partner-destined -> global.
// DUAL=true  (boundary 2): self-destined -> spare AND global; partner-
// destined -> global AND spare2 (this block re-reads it in phase 3).
template<bool DUAL>
__device__ __forceinline__ void exit_split(const float2* psi, float2* spare,
                                           float2* spare2,
                                           float2* __restrict__ dstBase,
                                           float4 g1, unsigned q,
                                           unsigned tid) {
#pragma unroll
    for (int m = 0; m < 4; ++m) {
        const unsigned jc = tid + (unsigned)m * TPB;  // bits 0..11
        const float2 x0 = psi[jc];
        const float2 x1 = psi[jc | 0x1000u];
        float2 A0, A1;
        A0.x =  g1.x*x0.x - g1.y*x0.y + g1.z*x1.x - g1.w*x1.y;
        A0.y =  g1.x*x0.y + g1.y*x0.x + g1.z*x1.y + g1.w*x1.x;
        A1.x = -g1.z*x0.x - g1.w*x0.y + g1.x*x1.x + g1.y*x1.y;
        A1.y = -g1.z*x0.y + g1.w*x0.x + g1.x*x1.y - g1.y*x1.x;
        const unsigned dA = sxmap(jc) ^ (q ? 0x1FFFu : 0u);
        const unsigned dB = dA ^ 0x3FFFu;             // ^Rinv(e12)
        // self item: bit13 == q (even local addr); partner item: odd local.
        const bool Arem = ((dA >> 13) != q);
        const unsigned ld = Arem ? dB : dA;
        const unsigned rd = Arem ? dA : dB;
        const float2  lv = Arem ? A1 : A0;
        const float2  rv = Arem ? A0 : A1;
        spare[(ld & 0x1FFFu) >> 1] = lv;              // self-destined -> LDS
        st_agent(dstBase + rd, rv);                   // partner-destined
        if (DUAL) {
            spare2[(rd & 0x1FFFu) >> 1] = rv;         // our phase-3 re-read
            st_agent(dstBase + ld, lv);               // partner's sP-even
        }
    }
}

// Pair-local phase barrier via MAGIC slots (r16 verbatim, proven). No
// memset: workspace re-poisoned per iteration resets slots; MAGIC halves
// differ so no repeated byte/word poison pattern aliases it. Visibility:
// compiler emits s_waitcnt vmcnt(0) before s_barrier, so all sc1 data
// stores are L3-visible before the magic store issues. 256 blocks all
// co-resident (1 blk/CU) -> spin-safe.
__device__ __forceinline__ void pair_sync(unsigned long long* mine,
                                          unsigned long long* theirs,
                                          unsigned tid) {
    __syncthreads();
    if (tid == 0) {
        __hip_atomic_store(mine, MAGIC64, __ATOMIC_RELAXED,
                           __HIP_MEMORY_SCOPE_AGENT);
        while (__hip_atomic_load(theirs, __ATOMIC_RELAXED,
                                 __HIP_MEMORY_SCOPE_AGENT) != MAGIC64)
            __builtin_amdgcn_s_sleep(1);
    }
    __syncthreads();
}

// All three phases in one kernel; block = (b, q).
__global__ __launch_bounds__(TPB) void k_fused(
    const float* __restrict__ states, const float* __restrict__ weights,
    const float* __restrict__ head_w, const float* __restrict__ head_b,
    float2* __restrict__ SA, float2* __restrict__ SB,
    unsigned long long* __restrict__ slots, float* __restrict__ out)
{
    extern __shared__ float2 psi[];          // [0,8192)      64 KB half-state
    float2* const spare  = psi + HALF;       // [8192,12288)  32 KB self stash
    float2* const spare2 = psi + HALF + HALF/2;  // [12288,16384) 32 KB rd stash
    __shared__ float2 vfac[NW][2];
    __shared__ float2 T1[128];
    __shared__ float2 T2[128];
    __shared__ float4 gcA[NW];        // layer-1 coefs
    __shared__ float4 gcB[NW];        // layer-2 coefs
    __shared__ float4 gcC[NW];        // layer-3 coefs
    __shared__ float wsum[TPB / 64];
    const unsigned gid = blockIdx.x, q = gid >> 7, b = gid & 127u;
    const unsigned tid = threadIdx.x;

    // ============ prologue: ALL gate coefs + out-init, one barrier =========
    if (tid < NW) {
        float4 g = fused_coef(weights, states, (int)b, 0, (int)tid);
        vfac[tid][0] = make_float2(g.x, g.y);
        vfac[tid][1] = make_float2(-g.z, g.w);
    } else if (tid >= 64 && tid < 64 + NW) {
        gcA[tid - 64] = fused_coef(weights, states, (int)b, 1, (int)(tid - 64));
    } else if (tid >= 128 && tid < 128 + NW) {
        gcB[tid - 128] = fused_coef(weights, states, (int)b, 2, (int)(tid - 128));
    } else if (tid >= 192 && tid < 192 + NW) {
        gcC[tid - 192] = fused_coef(weights, states, (int)b, 3, (int)(tid - 192));
    } else if (q == 0 && tid == 256) {
        __hip_atomic_store(out + b, head_b[0], __ATOMIC_RELAXED,
                           __HIP_MEMORY_SCOPE_AGENT);   // L3-visible init
    }
    __syncthreads();

    // ======================= phase 1: synth + layer 1 =======================
    if (tid < 128) {
        float2 p = make_float2(1.0f, 0.0f);
#pragma unroll
        for (int j = 0; j < 7; ++j)
            p = cmul(p, vfac[13 - j][(tid >> j) & 1u]);
        T1[tid] = p;
    } else if (tid < 256) {
        const unsigned u = tid - 128;
        float2 p = make_float2(1.0f, 0.0f);
#pragma unroll
        for (int j = 7; j < 14; ++j)
            p = cmul(p, vfac[13 - j][(u >> (j - 7)) & 1u]);
        T2[u] = p;
    }
    __syncthreads();

#pragma unroll
    for (int m = 0; m < 8; ++m) {
        const unsigned I  = tid + (unsigned)m * TPB;
        const unsigned If = I | (q << 13);
        const unsigned lo  = (If ^ (If >> 1)) & 0x0FFFu;
        const unsigned y12 = ((If >> 12) ^ (If >> 13) ^ If) & 1u;
        const unsigned y13 = ((If >> 13) ^ If) & 1u;
        const unsigned J = lo | (y12 << 12) | (y13 << 13);
        psi[I] = cmul(T1[J & 127u], T2[J >> 7]);
    }
    __syncthreads();                       // synth is cross-wave

    pass3h<0, 1, 7>(psi, gcA, tid);  WAVE_FENCE();   // exch: tid bits 0-2
    pass3h<3, 3, 1>(psi, gcA, tid);  WAVE_FENCE();   // exch: tid bits 3-5
    pass3h<6, 0, 0>(psi, gcA, tid);  __syncthreads(); // next exch: bits 6-8
    pass3h<9, 0, 0>(psi, gcA, tid);  __syncthreads();

    exit_split<false>(psi, spare, spare2, SA + (size_t)b * NSTATE,
                      gcA[1], q, tid);

    // ----------------------- boundary 1 (pair sync) ------------------------
    pair_sync(slots + (b * 4u + q),       slots + (b * 4u + (q ^ 1u)), tid);

    // ======================= phase 2: layer 2 ==============================
    {   // entry: deferred layer-1 wire-0 gate (pairs ^0x1FFF within half q).
        // Even local addr -> self-written (spare); odd -> partner (global).
        const float4 ge = gcA[0];
        const float2* src = SA + (size_t)b * NSTATE + (size_t)q * HALF;
        float2 fo[4], fe[4];
        unsigned icv[4];
#pragma unroll
        for (int m = 0; m < 4; ++m) {           // issue global loads first
            const unsigned ic = tid + (unsigned)m * TPB;   // bit12 = 0
            icv[m] = ic;
            const unsigned od = (ic & 1u) ? ic : (ic ^ 0x1FFFu);
            fo[m] = ld_agent(src + od);
        }
#pragma unroll
        for (int m = 0; m < 4; ++m) {           // LDS side
            const unsigned ic = icv[m];
            const unsigned ev = (ic & 1u) ? (ic ^ 0x1FFFu) : ic;
            fe[m] = spare[ev >> 1];
        }
#pragma unroll
        for (int m = 0; m < 4; ++m) {
            const unsigned ic = icv[m];
            const bool odd = (ic & 1u);
            const float2 f0 = odd ? fo[m] : fe[m];
            const float2 f1 = odd ? fe[m] : fo[m];
            const unsigned rc = (q ^ ic) & 1u;
            const float aar = ge.x, aai = rc ? -ge.y : ge.y;
            const float bbr = rc ? -ge.z : ge.z, bbi = ge.w;
            float2 oc, op;
            oc.x = aar*f0.x - aai*f0.y + bbr*f1.x - bbi*f1.y;
            oc.y = aar*f0.y + aai*f0.x + bbr*f1.y + bbi*f1.x;
            op.x = aar*f1.x + aai*f1.y - (bbr*f0.x + bbi*f0.y);
            op.y = aar*f1.y - aai*f1.x - (bbr*f0.y - bbi*f0.x);
            psi[ic]           = oc;
            psi[ic ^ 0x1FFFu] = op;
        }
    }
    __syncthreads();                       // entry is cross-wave

    pass3h<0, 1, 7>(psi, gcB, tid);  WAVE_FENCE();
    pass3h<3, 3, 1>(psi, gcB, tid);  WAVE_FENCE();
    pass3h<6, 0, 0>(psi, gcB, tid);  __syncthreads();
    pass3h<9, 0, 0>(psi, gcB, tid);  __syncthreads();

    exit_split<true>(psi, spare, spare2, SB + (size_t)b * NSTATE,
                     gcB[1], q, tid);

    // ----------------------- boundary 2 (pair sync) ------------------------
    pair_sync(slots + (256u + b * 4u + q), slots + (256u + b * 4u + (q ^ 1u)),
              tid);

    // ============== phase 3: layer 3 + contraction (h = q) =================
    const unsigned h = q;
    {   // entry: G[2,0] per half (rc twiddle) then G[3,0] across halves.
        // Own half: even from spare, odd from global. Partner half: even
        // from global (partner-written), odd from spare2 (we wrote those).
        const float4 ge = gcB[0];     // deferred layer-2 wire 0
        const float4 g0 = gcC[0];     // layer-3 wire 0
        const float ar = h ? -g0.z : g0.x;
        const float ai = h ?  g0.w : g0.y;
        const float br = h ?  g0.x : g0.z;
        const float bi = h ? -g0.y : g0.w;
        const float2* sQ = SB + (size_t)b * NSTATE + (size_t)q * HALF;
        const float2* sP = SB + (size_t)b * NSTATE + (size_t)(q ^ 1u) * HALF;
        float2 qog[4], pg[4], qe[4], ps[4];
        unsigned icv[4];
#pragma unroll
        for (int m = 0; m < 4; ++m) {           // issue 8 global loads first
            const unsigned ic = tid + (unsigned)m * TPB;   // bit12 = 0
            const unsigned jc = ic ^ 0x1FFFu;              // bit12 = 1
            icv[m] = ic;
            const unsigned od = (ic & 1u) ? ic : jc;   // own-half odd addr
            const unsigned pe = (ic & 1u) ? jc : ic;   // partner-half even
            qog[m] = ld_agent(sQ + od);
            pg[m]  = ld_agent(sP + pe);
        }
#pragma unroll
        for (int m = 0; m < 4; ++m) {           // LDS side
            const unsigned ic = icv[m];
            const unsigned jc = ic ^ 0x1FFFu;
            const unsigned ev = (ic & 1u) ? jc : ic;   // own-half even
            const unsigned po = (ic & 1u) ? ic : jc;   // partner-half odd
            qe[m] = spare[ev >> 1];
            ps[m] = spare2[po >> 1];
        }
#pragma unroll
        for (int m = 0; m < 4; ++m) {
            const unsigned ic = icv[m];
            const unsigned jc = ic ^ 0x1FFFu;
            const bool odd = (ic & 1u);
            const float2 o_i = odd ? qog[m] : qe[m];   // own half @ ic
            const float2 o_j = odd ? qe[m] : qog[m];   // own half @ jc
            const float2 p_i = odd ? ps[m] : pg[m];    // partner half @ ic
            const float2 p_j = odd ? pg[m] : ps[m];    // partner half @ jc
            // half0/half1 assignment (q-uniform select)
            const float2 f00 = q ? p_i : o_i;
            const float2 f01 = q ? p_j : o_j;
            const float2 f10 = q ? o_i : p_i;
            const float2 f11 = q ? o_j : p_j;
            const unsigned rc = ic & 1u;                   // q=0 twiddle
            float2 oc0, op0, oc1, op1;
            {   // G[2,0] on q=0 pair (rc)
                const float aar = ge.x, aai = rc ? -ge.y : ge.y;
                const float bbr = rc ? -ge.z : ge.z, bbi = ge.w;
                oc0.x = aar*f00.x - aai*f00.y + bbr*f01.x - bbi*f01.y;
                oc0.y = aar*f00.y + aai*f00.x + bbr*f01.y + bbi*f01.x;
                op0.x = aar*f01.x + aai*f01.y - (bbr*f00.x + bbi*f00.y);
                op0.y = aar*f01.y - aai*f01.x - (bbr*f00.y - bbi*f00.x);
            }
            {   // G[2,0] on q=1 pair (rc^1)
                const unsigned rx = rc ^ 1u;
                const float aar = ge.x, aai = rx ? -ge.y : ge.y;
                const float bbr = rx ? -ge.z : ge.z, bbi = ge.w;
                oc1.x = aar*f10.x - aai*f10.y + bbr*f11.x - bbi*f11.y;
                oc1.y = aar*f10.y + aai*f10.x + bbr*f11.y + bbi*f11.x;
                op1.x = aar*f11.x + aai*f11.y - (bbr*f10.x + bbi*f10.y);
                op1.y = aar*f11.y - aai*f11.x - (bbr*f10.y - bbi*f10.x);
            }
            float2 oA, oB;   // G[3,0] row h
            oA.x = ar*oc0.x - ai*oc0.y + br*oc1.x - bi*oc1.y;
            oA.y = ar*oc0.y + ai*oc0.x + br*oc1.y + bi*oc1.x;
            oB.x = ar*op0.x - ai*op0.y + br*op1.x - bi*op1.y;
            oB.y = ar*op0.y + ai*op0.x + br*op1.y + bi*op1.x;
            psi[ic] = oA;
            psi[jc] = oB;
        }
    }
    __syncthreads();                       // entry is cross-wave

    pass3h<0, 1, 7>(psi, gcC, tid);  WAVE_FENCE();
    pass3h<3, 3, 1>(psi, gcC, tid);  WAVE_FENCE();
    pass3h<6, 0, 0>(psi, gcC, tid);  __syncthreads();
    pass3h<9, 0, 0>(psi, gcC, tid);  __syncthreads();

    // wire-1 gate + contraction (k_rest r11 contraction, k = kk | h<<1)
    float hw[NW];
#pragma unroll
    for (int i = 0; i < NW; ++i) hw[i] = head_w[i];
    float H = 0.0f, H12 = 0.0f;
#pragma unroll
    for (int i = 0; i < NW; ++i) H += hw[i];
#pragma unroll
    for (int i = 2; i < NW; ++i) H12 += hw[i];

    const float4 g1 = gcC[1];   // layer-3 wire 1 (bit12)
    float acc = 0.0f;
#pragma unroll
    for (int m2 = 0; m2 < 4; ++m2) {
        const unsigned base = tid | ((unsigned)m2 << 10);  // bits 0..11
        float2 r[2];
        r[0] = psi[base];
        r[1] = psi[base | 0x1000u];
        gateN<2,1>(r, g1, 0u);
        float A = 0.0f;
        unsigned sfx = 0u;
#pragma unroll
        for (int p = 11; p >= 0; --p) {
            sfx ^= (base >> p) & 1u;
            if (sfx) A += hw[13 - p];
        }
        const unsigned P = sfx;
#pragma unroll
        for (int kk = 0; kk < 2; ++kk) {
            const unsigned u   = (unsigned)kk ^ h;   // J12 ^ J13
            const unsigned b13 = P ^ (unsigned)kk;   // parity J0..J12
            float sum = u ? (H12 - A) : A;
            if (u)   sum += hw[1];
            if (b13) sum += hw[0];
            const float cv = H - 2.0f * sum;
            acc += (r[kk].x * r[kk].x + r[kk].y * r[kk].y) * cv;
        }
    }
#pragma unroll
    for (int off = 32; off > 0; off >>= 1)
        acc += __shfl_down(acc, off, 64);
    if ((tid & 63u) == 0) wsum[tid >> 6] = acc;
    __syncthreads();
    if (tid == 0) {
        float tot = 0.0f;
#pragma unroll
        for (int i = 0; i < TPB / 64; ++i) tot += wsum[i];
        atomicAdd(out + b, tot);
    }
}

extern "C" void kernel_launch(void* const* d_in, const int* in_sizes, int n_in,
                              void* d_out, int out_size, void* d_ws, size_t ws_size,
                              hipStream_t stream) {
    const float* states  = (const float*)d_in[0];  // (128, 16384)
    const float* weights = (const float*)d_in[1];  // (4, 14, 2)
    const float* head_w  = (const float*)d_in[2];  // (1, 14)
    const float* head_b  = (const float*)d_in[3];  // (1,)
    float* out = (float*)d_out;                    // (128,)

    float2* SA = (float2*)d_ws;                        // 16 MB
    float2* SB = SA + (size_t)BATCH * NSTATE;          // next 16 MB
    unsigned long long* slots =
        (unsigned long long*)(SB + (size_t)BATCH * NSTATE);  // ~6 KB magic slots

    k_fused<<<2 * BATCH, TPB, SHB, stream>>>(states, weights, head_w, head_b,
                                             SA, SB, slots, out);
}